// Round 4
// baseline (59547.333 us; speedup 1.0000x reference)
//
#include <hip/hip_runtime.h>
#include <math.h>

#define TSTEPS 1024
#define BB 256
#define HH 256
#define INPUT 16
#define HBUF (BB*HH)

// ---- workspace layout (float offsets) ----
// Read-only after prep (via `wro`):
//   Wg1s  [256 j][128 kq][4 gate][4 ki]   (k = concat(h0 k<256, h1 k>=256))
//   Wg0hs [256 j][ 64 kq][4][4]
//   Wg0xs [256 j][  4 kq][4][4]
//   bs0/bs1 [256 j][4 gate]
// Mutable state (via `hrw`):
//   h0/h1 [2 buf][256 r][256 j]  (row-major: lane=row reads consecutive k)
//   c0T/c1T [256 j][256 r]       (transposed: coalesced cell update)
//   pbuf [2][8 jb][256 r]
#define OFF_WG1S  0u
#define OFF_WG0HS 524288u
#define OFF_WG0XS 786432u
#define OFF_BS0   802816u
#define OFF_BS1   803840u
#define OFF_H0    804864u
#define OFF_H1    935936u
#define OFF_C0T   1067008u
#define OFF_C1T   1132544u
#define OFF_PB    1198080u
#define WS_FLOATS 1202176u

typedef float4 f4;

__device__ __forceinline__ float fast_sigmoid(float v) {
    return __builtin_amdgcn_rcpf(1.0f + __expf(-v));
}
__device__ __forceinline__ float fast_tanh(float v) {
    return 1.0f - 2.0f * __builtin_amdgcn_rcpf(1.0f + __expf(2.0f * v));
}

__global__ __launch_bounds__(256) void prep_kernel(
    const float* __restrict__ Wih0, const float* __restrict__ Whh0,
    const float* __restrict__ bih0, const float* __restrict__ bhh0,
    const float* __restrict__ Wih1, const float* __restrict__ Whh1,
    const float* __restrict__ bih1, const float* __restrict__ bhh1,
    float* __restrict__ ws)
{
    for (unsigned idx = blockIdx.x * blockDim.x + threadIdx.x; idx < 804864u;
         idx += gridDim.x * blockDim.x) {
        if (idx < 524288u) {                       // Wg1s
            unsigned j = idx >> 11, rem = idx & 2047u;
            unsigned kq = rem >> 4, g = (rem >> 2) & 3u, ki = rem & 3u;
            unsigned k = kq * 4 + ki, row = g * 256 + j;
            ws[idx] = (k < 256u) ? Wih1[row * 256 + k] : Whh1[row * 256 + (k - 256u)];
        } else if (idx < 786432u) {                // Wg0hs
            unsigned i2 = idx - 524288u;
            unsigned j = i2 >> 10, rem = i2 & 1023u;
            unsigned kq = rem >> 4, g = (rem >> 2) & 3u, ki = rem & 3u;
            unsigned k = kq * 4 + ki, row = g * 256 + j;
            ws[idx] = Whh0[row * 256 + k];
        } else if (idx < 802816u) {                // Wg0xs
            unsigned i2 = idx - 786432u;
            unsigned j = i2 >> 6, rem = i2 & 63u;
            unsigned kq = rem >> 4, g = (rem >> 2) & 3u, ki = rem & 3u;
            unsigned k = kq * 4 + ki, row = g * 256 + j;
            ws[idx] = Wih0[row * 16 + k];
        } else if (idx < 803840u) {                // bs0
            unsigned i2 = idx - 802816u;
            unsigned j = i2 >> 2, g = i2 & 3u, row = g * 256 + j;
            ws[idx] = bih0[row] + bhh0[row];
        } else {                                   // bs1
            unsigned i2 = idx - 803840u;
            unsigned j = i2 >> 2, g = i2 & 3u, row = g * 256 + j;
            ws[idx] = bih1[row] + bhh1[row];
        }
    }
}

__global__ __launch_bounds__(256) void zero_state(float* __restrict__ ws) {
    const unsigned n = WS_FLOATS - OFF_H0;
    for (unsigned i = blockIdx.x * blockDim.x + threadIdx.x; i < n;
         i += gridDim.x * blockDim.x)
        ws[OFF_H0 + i] = 0.0f;
}

// nested-fma dot4 into acc
#define DOT1(ACC, H4, W4) \
    ACC = fmaf((H4).w, (W4).w, fmaf((H4).z, (W4).z, fmaf((H4).y, (W4).y, fmaf((H4).x, (W4).x, ACC))))

// 2-j x 4-gate dot: h4 against 8 float4 (j0 gates 0..3, j1 gates 0..3)
#define DOT2J(H4, W) do { \
    DOT1(acc0[0], H4, W[0]); DOT1(acc0[1], H4, W[1]); \
    DOT1(acc0[2], H4, W[2]); DOT1(acc0[3], H4, W[3]); \
    DOT1(acc1[0], H4, W[4]); DOT1(acc1[1], H4, W[5]); \
    DOT1(acc1[2], H4, W[6]); DOT1(acc1[3], H4, W[7]); \
  } while (0)

#define WLOAD2J(DST, KK) do { \
    const f4* w0_ = (const f4*)Wb0 + (size_t)(KK) * 4; \
    const f4* w1_ = (const f4*)Wb1 + (size_t)(KK) * 4; \
    DST[0] = w0_[0]; DST[1] = w0_[1]; DST[2] = w0_[2]; DST[3] = w0_[3]; \
    DST[4] = w1_[0]; DST[5] = w1_[1]; DST[6] = w1_[2]; DST[7] = w1_[3]; \
  } while (0)

// load 64-k h chunk (16 float4) for this lane's row
#define HLOAD(DST, C) do { \
    const float* hs_ = (((C) < 4) ? (srcA + (C) * 64) : (srcB + ((C) - 4) * 64)); \
    const f4* hp_ = (const f4*)(hs_ + (size_t)ra * HH); \
    _Pragma("unroll") \
    for (int q_ = 0; q_ < 16; ++q_) DST[q_] = hp_[q_]; \
  } while (0)

// LSTM/FC gemm core: NCHUNK 64-k chunks, register-pipelined h and W.
template<int NCHUNK>
__device__ __forceinline__ void rnn_dot_2j(
    const float* __restrict__ Wb0, const float* __restrict__ Wb1,
    const float* __restrict__ srcA, const float* __restrict__ srcB,
    int ra, float acc0[4], float acc1[4])
{
    const int NKQ = NCHUNK * 16;
    f4 hE[16], hO[16], wA[8], wB[8];
    HLOAD(hE, 0);
    WLOAD2J(wA, 0);
    #pragma unroll 1
    for (int cp = 0; cp < NCHUNK / 2; ++cp) {
        const int c0 = cp * 2;
        #pragma unroll
        for (int kq = 0; kq < 16; ++kq) {
            const int kk = c0 * 16 + kq;
            const int nk = (kk + 1 < NKQ) ? (kk + 1) : kk;
            if (kq & 1) { WLOAD2J(wA, nk); DOT2J(hE[kq], wB); }
            else        { WLOAD2J(wB, nk); DOT2J(hE[kq], wA); }
            if (kq == 7) HLOAD(hO, c0 + 1);
        }
        #pragma unroll
        for (int kq = 0; kq < 16; ++kq) {
            const int kk = (c0 + 1) * 16 + kq;
            const int nk = (kk + 1 < NKQ) ? (kk + 1) : kk;
            if (kq & 1) { WLOAD2J(wA, nk); DOT2J(hO[kq], wB); }
            else        { WLOAD2J(wB, nk); DOT2J(hO[kq], wA); }
            if (kq == 7 && (c0 + 2 < NCHUNK)) HLOAD(hE, c0 + 2);
        }
    }
}

// Block order (XCD round-robin balance):
//   blocks [0,32)    : FC-A fc1+relu+fc2 partials, step t-2  (~0.5M MAC)
//   blocks [32,160)  : layer-1 LSTM cell, step t-1           (~1.05M MAC)
//   blocks [160,288) : layer-0 LSTM cell, step t             (~0.56M MAC)
//   block  288       : FC-B final fc2 reduce, step t-3
__global__ __launch_bounds__(256, 2) void lstm_step(
    const float* __restrict__ x,
    const float* __restrict__ fc1w, const float* __restrict__ fc1b,
    const float* __restrict__ fc2w, const float* __restrict__ fc2b,
    const float* __restrict__ wro, float* __restrict__ hrw,
    float* __restrict__ out, int t)
{
    __shared__ float red[256];
    const int tid  = threadIdx.x;
    const int lane = tid & 63;
    const int wv   = __builtin_amdgcn_readfirstlane(tid >> 6);
    const int blk  = blockIdx.x;

    float* h0 = hrw + OFF_H0;
    float* h1 = hrw + OFF_H1;

    if (blk >= 32 && blk < 288) {
        // ---------------- LSTM roles ----------------
        const bool isL1 = (blk < 160);
        const int  s    = isL1 ? (t - 1) : t;
        if (s < 0 || s >= TSTEPS) return;
        const int bb = isL1 ? (blk - 32) : (blk - 160);
        const int rb = bb >> 5;               // 0..3
        const int jb = bb & 31;               // 0..31
        const int r0 = rb * 64;
        const int j0 = jb * 8 + wv * 2;       // wave's two j columns (uniform)
        const int ra = r0 + lane;

        const float* Wg  = wro + (isL1 ? OFF_WG1S : OFF_WG0HS);
        const float* bs  = wro + (isL1 ? OFF_BS1 : OFF_BS0);
        const float* srcA = isL1 ? (h0 + (s & 1) * HBUF)
                                 : (h0 + ((s + 1) & 1) * HBUF);
        const float* srcB = h1 + ((s + 1) & 1) * HBUF;   // h1(s-1), L1 only
        float* hw = isL1 ? (h1 + (s & 1) * HBUF)
                         : (h0 + (s & 1) * HBUF);
        float* cT = hrw + (isL1 ? OFF_C1T : OFF_C0T);

        const int wstride = isL1 ? 2048 : 1024;
        const float* Wb0 = Wg + (size_t)j0 * wstride;
        const float* Wb1 = Wb0 + wstride;

        float acc0[4] = {0.f, 0.f, 0.f, 0.f};
        float acc1[4] = {0.f, 0.f, 0.f, 0.f};

        // ---- L0 input projection (K=16 from x_t) ----
        if (!isL1) {
            const float* xr = x + (size_t)ra * (TSTEPS * INPUT) + (size_t)s * INPUT;
            f4 xv[4];
            #pragma unroll
            for (int q = 0; q < 4; ++q) xv[q] = *(const f4*)(xr + q * 4);
            const float* Xb0 = wro + OFF_WG0XS + (size_t)j0 * 64;
            const float* Xb1 = Xb0 + 64;
            #pragma unroll
            for (int kk = 0; kk < 4; ++kk) {
                f4 w[8];
                { const f4* w0_ = (const f4*)Xb0 + kk * 4;
                  const f4* w1_ = (const f4*)Xb1 + kk * 4;
                  w[0]=w0_[0]; w[1]=w0_[1]; w[2]=w0_[2]; w[3]=w0_[3];
                  w[4]=w1_[0]; w[5]=w1_[1]; w[6]=w1_[2]; w[7]=w1_[3]; }
                DOT2J(xv[kk], w);
            }
        }

        if (isL1) rnn_dot_2j<8>(Wb0, Wb1, srcA, srcB, ra, acc0, acc1);
        else      rnn_dot_2j<4>(Wb0, Wb1, srcA, srcA, ra, acc0, acc1);

        // ---- cell update (gate order i,f,g,o) ----
        #pragma unroll
        for (int jj = 0; jj < 2; ++jj) {
            const int j = j0 + jj;
            float* acc = jj ? acc1 : acc0;
            float ig = fast_sigmoid(acc[0] + bs[j * 4 + 0]);
            float fg = fast_sigmoid(acc[1] + bs[j * 4 + 1]);
            float gg = fast_tanh   (acc[2] + bs[j * 4 + 2]);
            float og = fast_sigmoid(acc[3] + bs[j * 4 + 3]);
            float cp = cT[j * BB + ra];
            float cn = fg * cp + ig * gg;
            cT[j * BB + ra] = cn;                           // coalesced
            hw[(size_t)ra * HH + j] = og * fast_tanh(cn);   // row-major scatter
        }
    } else if (blk < 32) {
        // ---------------- FC-A: fc1 + relu + fc2 partials for step t-2 ----------------
        const int tt = t - 2;
        if (tt < 0 || tt >= TSTEPS) return;
        const int rb = blk >> 3, jb = blk & 7;
        const int r0 = rb * 64;
        const int j0 = jb * 32 + wv * 8;      // wave's 8 fc1 outputs (uniform)
        const int ra = r0 + lane;
        const float* hs = h1 + (tt & 1) * HBUF;   // row-major [r][k]

        float acc[8] = {0.f,0.f,0.f,0.f,0.f,0.f,0.f,0.f};

        {   // same register-pipelined scheme: 4 chunks, 8-j W tiles
            const float* srcA = hs;
            f4 hE[16], hO[16], wA[8], wB[8];
            #define WLOADF(DST, KK) do { \
                _Pragma("unroll") \
                for (int jj_ = 0; jj_ < 8; ++jj_) \
                    DST[jj_] = *((const f4*)(fc1w + (size_t)(j0 + jj_) * HH) + (KK)); \
              } while (0)
            #define DOTF(H4, W) do { \
                _Pragma("unroll") \
                for (int jj_ = 0; jj_ < 8; ++jj_) DOT1(acc[jj_], H4, W[jj_]); \
              } while (0)
            { const f4* hp_ = (const f4*)(srcA + (size_t)ra * HH);
              #pragma unroll
              for (int q = 0; q < 16; ++q) hE[q] = hp_[q]; }
            WLOADF(wA, 0);
            #pragma unroll 1
            for (int cp = 0; cp < 2; ++cp) {
                const int c0 = cp * 2;
                #pragma unroll
                for (int kq = 0; kq < 16; ++kq) {
                    const int kk = c0 * 16 + kq;
                    const int nk = (kk + 1 < 64) ? (kk + 1) : kk;
                    if (kq & 1) { WLOADF(wA, nk); DOTF(hE[kq], wB); }
                    else        { WLOADF(wB, nk); DOTF(hE[kq], wA); }
                    if (kq == 7) {
                        const f4* hp_ = (const f4*)(srcA + (c0 + 1) * 64 + (size_t)ra * HH);
                        #pragma unroll
                        for (int q = 0; q < 16; ++q) hO[q] = hp_[q];
                    }
                }
                #pragma unroll
                for (int kq = 0; kq < 16; ++kq) {
                    const int kk = (c0 + 1) * 16 + kq;
                    const int nk = (kk + 1 < 64) ? (kk + 1) : kk;
                    if (kq & 1) { WLOADF(wA, nk); DOTF(hO[kq], wB); }
                    else        { WLOADF(wB, nk); DOTF(hO[kq], wA); }
                    if (kq == 7 && (c0 + 2 < 4)) {
                        const f4* hp_ = (const f4*)(srcA + (c0 + 2) * 64 + (size_t)ra * HH);
                        #pragma unroll
                        for (int q = 0; q < 16; ++q) hE[q] = hp_[q];
                    }
                }
            }
        }

        float p = 0.f;
        #pragma unroll
        for (int jj = 0; jj < 8; ++jj) {
            const int j = j0 + jj;
            float v = acc[jj] + fc1b[j];
            v = v > 0.f ? v : 0.f;
            p = fmaf(fc2w[j], v, p);
        }
        red[wv * 64 + lane] = p;
        __syncthreads();
        if (tid < 64) {
            float s4 = red[tid] + red[64 + tid] + red[128 + tid] + red[192 + tid];
            hrw[OFF_PB + (unsigned)(t & 1) * 2048u + (unsigned)jb * 256u + r0 + tid] = s4;
        }
    } else {
        // ---------------- FC-B: final fc2 reduce for step t-3 ----------------
        const int tt = t - 3;
        if (tt < 0 || tt >= TSTEPS) return;
        const float* pb = hrw + OFF_PB + (unsigned)((t - 1) & 1) * 2048u;
        float s = fc2b[0];
        #pragma unroll
        for (int jb = 0; jb < 8; ++jb) s += pb[jb * 256 + tid];
        out[(size_t)tid * TSTEPS + tt] = s;
    }
}

extern "C" void kernel_launch(void* const* d_in, const int* in_sizes, int n_in,
                              void* d_out, int out_size, void* d_ws, size_t ws_size,
                              hipStream_t stream)
{
    const float* x    = (const float*)d_in[0];
    const float* Wih0 = (const float*)d_in[1];
    const float* Whh0 = (const float*)d_in[2];
    const float* bih0 = (const float*)d_in[3];
    const float* bhh0 = (const float*)d_in[4];
    const float* Wih1 = (const float*)d_in[5];
    const float* Whh1 = (const float*)d_in[6];
    const float* bih1 = (const float*)d_in[7];
    const float* bhh1 = (const float*)d_in[8];
    const float* fc1w = (const float*)d_in[9];
    const float* fc1b = (const float*)d_in[10];
    const float* fc2w = (const float*)d_in[11];
    const float* fc2b = (const float*)d_in[12];
    float* ws  = (float*)d_ws;
    float* out = (float*)d_out;

    prep_kernel<<<512, 256, 0, stream>>>(Wih0, Whh0, bih0, bhh0,
                                         Wih1, Whh1, bih1, bhh1, ws);
    zero_state<<<512, 256, 0, stream>>>(ws);

    for (int t = 0; t < TSTEPS + 3; ++t)
        lstm_step<<<289, 256, 0, stream>>>(x, fc1w, fc1b, fc2w, fc2b,
                                           ws, ws, out, t);
}

// Round 5
// 37653.464 us; speedup vs baseline: 1.5815x; 1.5815x over previous
//
#include <hip/hip_runtime.h>
#include <math.h>

#define TSTEPS 1024
#define BB 256
#define HH 256
#define INPUT 16
#define HBUF (BB*HH)

// ---- workspace layout (float offsets) ----
// Read-only after prep (via `wro`):
//   Wg1s  [256 j][128 kq][4 gate][4 ki]   (k = concat(h0 k<256, h1 k>=256))
//   Wg0hs [256 j][ 64 kq][4][4]
//   Wg0xs [256 j][  4 kq][4][4]
//   bs0/bs1 [256 j][4 gate]
// Mutable state (via `hrw`):
//   h0/h1 [2 buf][256 r][256 j]  (row-major: staged reads contiguous in k)
//   c0T/c1T [256 j][256 r]       (transposed: coalesced cell update)
//   pbuf [2][8 jb][256 r]
#define OFF_WG1S  0u
#define OFF_WG0HS 524288u
#define OFF_WG0XS 786432u
#define OFF_BS0   802816u
#define OFF_BS1   803840u
#define OFF_H0    804864u
#define OFF_H1    935936u
#define OFF_C0T   1067008u
#define OFF_C1T   1132544u
#define OFF_PB    1198080u
#define WS_FLOATS 1202176u

typedef float4 f4;

__device__ __forceinline__ float fast_sigmoid(float v) {
    return __builtin_amdgcn_rcpf(1.0f + __expf(-v));
}
__device__ __forceinline__ float fast_tanh(float v) {
    return 1.0f - 2.0f * __builtin_amdgcn_rcpf(1.0f + __expf(2.0f * v));
}

#define DOT1(ACC, H4, W4) \
    ACC = fmaf((H4).w, (W4).w, fmaf((H4).z, (W4).z, fmaf((H4).y, (W4).y, fmaf((H4).x, (W4).x, ACC))))

__global__ __launch_bounds__(256) void prep_kernel(
    const float* __restrict__ Wih0, const float* __restrict__ Whh0,
    const float* __restrict__ bih0, const float* __restrict__ bhh0,
    const float* __restrict__ Wih1, const float* __restrict__ Whh1,
    const float* __restrict__ bih1, const float* __restrict__ bhh1,
    float* __restrict__ ws)
{
    for (unsigned idx = blockIdx.x * blockDim.x + threadIdx.x; idx < 804864u;
         idx += gridDim.x * blockDim.x) {
        if (idx < 524288u) {                       // Wg1s
            unsigned j = idx >> 11, rem = idx & 2047u;
            unsigned kq = rem >> 4, g = (rem >> 2) & 3u, ki = rem & 3u;
            unsigned k = kq * 4 + ki, row = g * 256 + j;
            ws[idx] = (k < 256u) ? Wih1[row * 256 + k] : Whh1[row * 256 + (k - 256u)];
        } else if (idx < 786432u) {                // Wg0hs
            unsigned i2 = idx - 524288u;
            unsigned j = i2 >> 10, rem = i2 & 1023u;
            unsigned kq = rem >> 4, g = (rem >> 2) & 3u, ki = rem & 3u;
            unsigned k = kq * 4 + ki, row = g * 256 + j;
            ws[idx] = Whh0[row * 256 + k];
        } else if (idx < 802816u) {                // Wg0xs
            unsigned i2 = idx - 786432u;
            unsigned j = i2 >> 6, rem = i2 & 63u;
            unsigned kq = rem >> 4, g = (rem >> 2) & 3u, ki = rem & 3u;
            unsigned k = kq * 4 + ki, row = g * 256 + j;
            ws[idx] = Wih0[row * 16 + k];
        } else if (idx < 803840u) {                // bs0
            unsigned i2 = idx - 802816u;
            unsigned j = i2 >> 2, g = i2 & 3u, row = g * 256 + j;
            ws[idx] = bih0[row] + bhh0[row];
        } else {                                   // bs1
            unsigned i2 = idx - 803840u;
            unsigned j = i2 >> 2, g = i2 & 3u, row = g * 256 + j;
            ws[idx] = bih1[row] + bhh1[row];
        }
    }
}

__global__ __launch_bounds__(256) void zero_state(float* __restrict__ ws) {
    const unsigned n = WS_FLOATS - OFF_H0;
    for (unsigned i = blockIdx.x * blockDim.x + threadIdx.x; i < n;
         i += gridDim.x * blockDim.x)
        ws[OFF_H0 + i] = 0.0f;
}

// Block map (dispatch round-robin => round 1: blocks 0..255 (L1), round 2:
// blocks 256..511 (L0) pair 1:1 on the same CUs, round 3: 33 light FC blocks):
//   blocks [0,256)   : layer-1 LSTM, step t-1.  64r x 4j, K=512. wave = 1 j.
//   blocks [256,512) : layer-0 LSTM, step t.    64r x 4j, K=256+16. wave = 1 j.
//   blocks [512,544) : FC-A fc1+relu+fc2 partials, step t-2. 64r x 32j, wave = 8 j.
//   block  544       : FC-B final fc2 reduce, step t-3.
__global__ __launch_bounds__(256, 3) void lstm_step(
    const float* __restrict__ x,
    const float* __restrict__ fc1w, const float* __restrict__ fc1b,
    const float* __restrict__ fc2w, const float* __restrict__ fc2b,
    const float* __restrict__ wro, float* __restrict__ hrw,
    float* __restrict__ out, int t)
{
    __shared__ __align__(16) float tile[64 * 132];   // [64 r][128 k + pad4]
    __shared__ float red[256];
    const int tid  = threadIdx.x;
    const int lane = tid & 63;
    const int wv   = __builtin_amdgcn_readfirstlane(tid >> 6);
    const int blk  = blockIdx.x;

    float* h0 = hrw + OFF_H0;
    float* h1 = hrw + OFF_H1;

    if (blk < 512) {
        // ---------------- LSTM roles ----------------
        const bool isL1 = (blk < 256);
        const int  s    = isL1 ? (t - 1) : t;
        if (s < 0 || s >= TSTEPS) return;
        const int bb = isL1 ? blk : (blk - 256);
        const int rb = bb >> 6;               // 0..3
        const int jb = bb & 63;               // 0..63
        const int r0 = rb * 64;
        const int j  = jb * 4 + wv;           // wave's single j column (uniform)
        const int ra = r0 + lane;

        const float* bs   = wro + (isL1 ? OFF_BS1 : OFF_BS0);
        const float* srcA = h0 + ((t - 1) & 1) * HBUF;        // h0(t-1) for both roles
        const float* srcB = h1 + (t & 1) * HBUF;              // h1(t-2), L1 only
        float* hw = isL1 ? (h1 + ((t - 1) & 1) * HBUF)
                         : (h0 + (t & 1) * HBUF);
        float* cT = hrw + (isL1 ? OFF_C1T : OFF_C0T);

        const float* Wg = wro + (isL1 ? OFF_WG1S : OFF_WG0HS);
        const int wstride = isL1 ? 2048 : 1024;
        const int nchunk  = isL1 ? 4 : 2;     // 128-k chunks

        float acc[4] = {0.f, 0.f, 0.f, 0.f};
        f4 st[8];
        f4 xv[4];

        // issue x loads early (L0 only), consumed after the main loop
        if (!isL1) {
            const float* xr = x + (size_t)ra * (TSTEPS * INPUT) + (size_t)s * INPUT;
            #pragma unroll
            for (int q = 0; q < 4; ++q) xv[q] = *(const f4*)(xr + q * 4);
        }

        // stage 128-k chunk: thread f -> (r = f>>5, kq = f&31), coalesced rows
        auto stage_ld = [&](int c) {
            const float* src = (isL1 && c >= 2) ? (srcB + (c - 2) * 128)
                                                : (srcA + c * 128);
            #pragma unroll
            for (int i = 0; i < 8; ++i) {
                int f = tid + i * 256;
                int r = f >> 5, kq = f & 31;
                st[i] = *(const f4*)(src + (size_t)(r0 + r) * HH + kq * 4);
            }
        };
        auto stage_st = [&]() {
            #pragma unroll
            for (int i = 0; i < 8; ++i) {
                int f = tid + i * 256;
                int r = f >> 5, kq = f & 31;
                *(f4*)&tile[r * 132 + kq * 4] = st[i];
            }
        };

        stage_ld(0);
        for (int c = 0; c < nchunk; ++c) {
            __syncthreads();                  // readers of previous chunk done
            stage_st();
            if (c + 1 < nchunk) stage_ld(c + 1);   // hide next global loads
            __syncthreads();                  // tile ready
            const f4* wp = (const f4*)(Wg + (size_t)j * wstride + (size_t)c * 512);
            #pragma unroll
            for (int kq = 0; kq < 32; ++kq) {
                f4 hv = *(const f4*)&tile[lane * 132 + kq * 4];
                f4 w0 = wp[kq * 4 + 0];
                f4 w1 = wp[kq * 4 + 1];
                f4 w2 = wp[kq * 4 + 2];
                f4 w3 = wp[kq * 4 + 3];
                DOT1(acc[0], hv, w0);
                DOT1(acc[1], hv, w1);
                DOT1(acc[2], hv, w2);
                DOT1(acc[3], hv, w3);
            }
        }

        // ---- L0 input projection (K=16 from x_t) ----
        if (!isL1) {
            const f4* xp = (const f4*)(wro + OFF_WG0XS + (size_t)j * 64);
            #pragma unroll
            for (int kq = 0; kq < 4; ++kq) {
                DOT1(acc[0], xv[kq], xp[kq * 4 + 0]);
                DOT1(acc[1], xv[kq], xp[kq * 4 + 1]);
                DOT1(acc[2], xv[kq], xp[kq * 4 + 2]);
                DOT1(acc[3], xv[kq], xp[kq * 4 + 3]);
            }
        }

        // ---- cell update (gate order i,f,g,o) ----
        {
            float ig = fast_sigmoid(acc[0] + bs[j * 4 + 0]);
            float fg = fast_sigmoid(acc[1] + bs[j * 4 + 1]);
            float gg = fast_tanh   (acc[2] + bs[j * 4 + 2]);
            float og = fast_sigmoid(acc[3] + bs[j * 4 + 3]);
            float cp = cT[j * BB + ra];
            float cn = fg * cp + ig * gg;
            cT[j * BB + ra] = cn;                           // coalesced
            hw[(size_t)ra * HH + j] = og * fast_tanh(cn);   // scatter (4B/line)
        }
    } else if (blk < 544) {
        // ---------------- FC-A: fc1 + relu + fc2 partials for step t-2 ----------------
        const int tt = t - 2;
        if (tt < 0 || tt >= TSTEPS) return;
        const int bb = blk - 512;             // 0..31
        const int rb = bb >> 3, jb = bb & 7;
        const int r0 = rb * 64;
        const int j0 = jb * 32 + wv * 8;      // wave's 8 fc1 outputs (uniform)
        const float* hs = h1 + (t & 1) * HBUF;   // h1(t-2), parity (t-2)&1 == t&1

        float acc[8] = {0.f,0.f,0.f,0.f,0.f,0.f,0.f,0.f};
        f4 st[8];

        auto stage_ld = [&](int c) {
            #pragma unroll
            for (int i = 0; i < 8; ++i) {
                int f = tid + i * 256;
                int r = f >> 5, kq = f & 31;
                st[i] = *(const f4*)(hs + (size_t)(r0 + r) * HH + c * 128 + kq * 4);
            }
        };
        auto stage_st = [&]() {
            #pragma unroll
            for (int i = 0; i < 8; ++i) {
                int f = tid + i * 256;
                int r = f >> 5, kq = f & 31;
                *(f4*)&tile[r * 132 + kq * 4] = st[i];
            }
        };

        stage_ld(0);
        for (int c = 0; c < 2; ++c) {
            __syncthreads();
            stage_st();
            if (c == 0) stage_ld(1);
            __syncthreads();
            const int kb = c * 32;
            #pragma unroll
            for (int kq = 0; kq < 32; ++kq) {
                f4 hv = *(const f4*)&tile[lane * 132 + kq * 4];
                #pragma unroll
                for (int jj = 0; jj < 8; ++jj) {
                    f4 w = *((const f4*)(fc1w + (size_t)(j0 + jj) * HH) + kb + kq);
                    DOT1(acc[jj], hv, w);
                }
            }
        }
        float p = 0.f;
        #pragma unroll
        for (int jj = 0; jj < 8; ++jj) {
            const int jx = j0 + jj;
            float v = acc[jj] + fc1b[jx];
            v = v > 0.f ? v : 0.f;
            p = fmaf(fc2w[jx], v, p);
        }
        __syncthreads();
        red[wv * 64 + lane] = p;
        __syncthreads();
        if (tid < 64) {
            float s4 = red[tid] + red[64 + tid] + red[128 + tid] + red[192 + tid];
            hrw[OFF_PB + (unsigned)(t & 1) * 2048u + (unsigned)jb * 256u + r0 + tid] = s4;
        }
    } else {
        // ---------------- FC-B: final fc2 reduce for step t-3 ----------------
        const int tt = t - 3;
        if (tt < 0 || tt >= TSTEPS) return;
        const float* pb = hrw + OFF_PB + (unsigned)((t - 1) & 1) * 2048u;
        float s = fc2b[0];
        #pragma unroll
        for (int jb = 0; jb < 8; ++jb) s += pb[jb * 256 + tid];
        out[(size_t)tid * TSTEPS + tt] = s;
    }
}

extern "C" void kernel_launch(void* const* d_in, const int* in_sizes, int n_in,
                              void* d_out, int out_size, void* d_ws, size_t ws_size,
                              hipStream_t stream)
{
    const float* x    = (const float*)d_in[0];
    const float* Wih0 = (const float*)d_in[1];
    const float* Whh0 = (const float*)d_in[2];
    const float* bih0 = (const float*)d_in[3];
    const float* bhh0 = (const float*)d_in[4];
    const float* Wih1 = (const float*)d_in[5];
    const float* Whh1 = (const float*)d_in[6];
    const float* bih1 = (const float*)d_in[7];
    const float* bhh1 = (const float*)d_in[8];
    const float* fc1w = (const float*)d_in[9];
    const float* fc1b = (const float*)d_in[10];
    const float* fc2w = (const float*)d_in[11];
    const float* fc2b = (const float*)d_in[12];
    float* ws  = (float*)d_ws;
    float* out = (float*)d_out;

    prep_kernel<<<512, 256, 0, stream>>>(Wih0, Whh0, bih0, bhh0,
                                         Wih1, Whh1, bih1, bhh1, ws);
    zero_state<<<512, 256, 0, stream>>>(ws);

    for (int t = 0; t < TSTEPS + 3; ++t)
        lstm_step<<<545, 256, 0, stream>>>(x, fc1w, fc1b, fc2w, fc2b,
                                           ws, ws, out, t);
}